// Round 5
// baseline (233.987 us; speedup 1.0000x reference)
//
#include <hip/hip_runtime.h>
#include <stdint.h>

// LinearAttention MI355X round 5: fuse k_out+k_y into k_oy (out-chunk stays in LDS,
// y accumulated in AGPRs across heads). k_kv outputs kv TRANSPOSED [e][d] and uses
// BK=64. k_qkv / k_tx / k_convW unchanged from R4.
// B=8, DIM=256, HEADS=8, DHEAD=64, HID=512, NPIX=4096.

#define NPIX 4096
#define HIDC 512
#define DIMC 256
#define BATCH 8

typedef __attribute__((ext_vector_type(8))) short bf16x8;
typedef __attribute__((ext_vector_type(4))) float f32x4;
typedef __attribute__((ext_vector_type(16))) float f32x16;

__device__ __forceinline__ float bf2f(unsigned short h) {
    unsigned int u = ((unsigned int)h) << 16; float f;
    __builtin_memcpy(&f, &u, 4); return f;
}
__device__ __forceinline__ unsigned short f2bf(float f) {
    unsigned int u; __builtin_memcpy(&u, &f, 4);
    u += 0x7fffu + ((u >> 16) & 1u);
    return (unsigned short)(u >> 16);
}
__device__ __forceinline__ float elu1(float x) {
    return x > 0.f ? x + 1.f : __expf(x);
}
__device__ __forceinline__ void gl16(const unsigned short* g, unsigned short* l) {
    __builtin_amdgcn_global_load_lds(
        (__attribute__((address_space(1))) const void*)g,
        (__attribute__((address_space(3))) void*)l, 16, 0, 0);
}

// ---------------- K0a: weight conversion ----------------
__global__ __launch_bounds__(256) void k_convW(
    const float* __restrict__ Wqkv, const float* __restrict__ Wout,
    unsigned short* __restrict__ Wb, unsigned short* __restrict__ Wob)
{
    int i4 = (blockIdx.x * 256 + threadIdx.x) * 4;
    const int NW1 = 1536 * 256;
    float4 v; unsigned short* dst;
    if (i4 < NW1) { v = *(const float4*)&Wqkv[i4]; dst = Wb + i4; }
    else { int j = i4 - NW1; v = *(const float4*)&Wout[j]; dst = Wob + j; }
    ushort4 o; o.x = f2bf(v.x); o.y = f2bf(v.y); o.z = f2bf(v.z); o.w = f2bf(v.w);
    *(ushort4*)dst = o;
}

// ---------------- K0b: x transpose+convert ----------------
__global__ __launch_bounds__(256) void k_tx(
    const float* __restrict__ x, unsigned short* __restrict__ xT)
{
    __shared__ float tile[32][33];
    const int n0 = blockIdx.x * 32, c0 = blockIdx.y * 32, b = blockIdx.z;
    const int t = threadIdx.x;
    const int r = t >> 3, c4 = (t & 7) * 4;
    float4 v = *(const float4*)&x[((size_t)b * DIMC + c0 + r) * NPIX + n0 + c4];
    tile[r][c4 + 0] = v.x; tile[r][c4 + 1] = v.y;
    tile[r][c4 + 2] = v.z; tile[r][c4 + 3] = v.w;
    __syncthreads();
    ushort4 o;
    unsigned short* op = (unsigned short*)&o;
#pragma unroll
    for (int i = 0; i < 4; i++) op[i] = f2bf(tile[c4 + i][r]);
    *(ushort4*)&xT[((size_t)b * NPIX + n0 + r) * DIMC + c0 + c4] = o;
}

// ---------------- K1: qkv MFMA GEMM (unchanged from R4) ----------------
__global__ __launch_bounds__(256) void k_qkv(
    const unsigned short* __restrict__ xT,   // B x 4096 x 256
    const unsigned short* __restrict__ Wb,   // 1536 x 256
    const float* __restrict__ cmp,           // B x 4096
    const float* __restrict__ csp,
    unsigned short* __restrict__ qT,         // B x 4096 x 512 (pixel-major)
    unsigned short* __restrict__ kb,         // B x 512 x 4096 (channel-major)
    unsigned short* __restrict__ vb)         // B x 512 x 4096
{
    const int b  = blockIdx.z;
    const int m0 = blockIdx.x * 128;
    const int n0 = blockIdx.y * 128;
    const int t = threadIdx.x;
    const int wave = t >> 6, lane = t & 63;
    const int wm = wave >> 1, wn = wave & 1;
    const int l31 = lane & 31, lhi = lane >> 5;
    const int sect = n0 >> 9;

    __shared__ unsigned short As[128 * 64];
    __shared__ unsigned short Bs[128 * 64];

    const unsigned short* Ag = xT + ((size_t)b * NPIX + m0) * DIMC;
    const unsigned short* Bg = Wb + (size_t)n0 * DIMC;

    const unsigned short* mArr = (sect == 0) ? As : Bs;
    const unsigned short* nArr = (sect == 0) ? Bs : As;

    f32x16 acc[2][2];
#pragma unroll
    for (int i = 0; i < 2; i++)
#pragma unroll
        for (int j = 0; j < 2; j++)
#pragma unroll
            for (int r = 0; r < 16; r++) acc[i][j][r] = 0.f;

    const int r8  = lane >> 3;
    const int jg8 = (((lane & 7) ^ r8) & 7) * 8;
    const int xsw = (l31 & 7);

    for (int k0 = 0; k0 < DIMC; k0 += 64) {
#pragma unroll
        for (int i = 0; i < 4; i++) {
            const int rowg = wave * 32 + i * 8;
            gl16(&Ag[(size_t)(rowg + r8) * DIMC + k0 + jg8], &As[rowg * 64]);
            gl16(&Bg[(size_t)(rowg + r8) * DIMC + k0 + jg8], &Bs[rowg * 64]);
        }
        __syncthreads();
#pragma unroll
        for (int ks = 0; ks < 4; ks++) {
            const int coff = ((ks * 2 + lhi) ^ xsw) * 8;
            bf16x8 af[2], bfg[2];
#pragma unroll
            for (int fm = 0; fm < 2; fm++)
                af[fm] = *(const bf16x8*)&mArr[(wm * 64 + fm * 32 + l31) * 64 + coff];
#pragma unroll
            for (int fn = 0; fn < 2; fn++)
                bfg[fn] = *(const bf16x8*)&nArr[(wn * 64 + fn * 32 + l31) * 64 + coff];
#pragma unroll
            for (int fm = 0; fm < 2; fm++)
#pragma unroll
                for (int fn = 0; fn < 2; fn++)
                    acc[fm][fn] = __builtin_amdgcn_mfma_f32_32x32x16_bf16(
                        af[fm], bfg[fn], acc[fm][fn], 0, 0, 0);
        }
        __syncthreads();
    }

    const float cs = *csp;
    if (sect == 0) {
#pragma unroll
        for (int fm = 0; fm < 2; fm++) {
            const int pbase = m0 + wm * 64 + fm * 32;
#pragma unroll
            for (int fn = 0; fn < 2; fn++) {
                const int o = n0 + wn * 64 + fn * 32 + l31;
#pragma unroll
                for (int r = 0; r < 16; r++) {
                    int prow = pbase + (r & 3) + 8 * (r >> 2) + 4 * lhi;
                    qT[((size_t)b * NPIX + prow) * HIDC + o] = f2bf(elu1(acc[fm][fn][r]));
                }
            }
        }
    } else {
        unsigned short* dstb = (sect == 1) ? kb : vb;
#pragma unroll
        for (int fm = 0; fm < 2; fm++) {
            const int obase = (n0 & 511) + wm * 64 + fm * 32;
#pragma unroll
            for (int fn = 0; fn < 2; fn++) {
                const int pixel = m0 + wn * 64 + fn * 32 + l31;
                float g = 1.f;
                if (sect == 1) g = 1.f + cs * cmp[(size_t)b * NPIX + pixel];
#pragma unroll
                for (int r = 0; r < 16; r++) {
                    int orow = obase + (r & 3) + 8 * (r >> 2) + 4 * lhi;
                    float val = acc[fm][fn][r];
                    if (sect == 1) val = elu1(val) * g;
                    dstb[((size_t)b * HIDC + orow) * NPIX + pixel] = f2bf(val);
                }
            }
        }
    }
}

// ---------------- K2: kv + ksum (BK=64, TRANSPOSED kv output [e][d]) --------
#define LKV 72
__global__ __launch_bounds__(256) void k_kv(
    const unsigned short* __restrict__ kb, const unsigned short* __restrict__ vb,
    float* __restrict__ kvT,     // 64bh x [e][d], zeroed
    float* __restrict__ ksum)    // 64bh x 64, zeroed
{
    const int bh = blockIdx.y, nc = blockIdx.x;
    const int t = threadIdx.x, wave = t >> 6, lane = t & 63;
    const int lrow = lane & 15, quad = lane >> 4;

    __shared__ unsigned short ks[64 * LKV];
    __shared__ unsigned short vs[64 * LKV];

    const size_t base = (size_t)bh * 64 * NPIX;
    f32x4 acc[4];
#pragma unroll
    for (int i = 0; i < 4; i++) acc[i] = (f32x4){0.f, 0.f, 0.f, 0.f};
    float ksacc = 0.f;

    const int row = t >> 2, c8 = (t & 3) * 8;   // each thread: 2 chunks (c8, c8+32)

    for (int step = 0; step < 8; step++) {
        const int ncol = nc * 512 + step * 64;
        const size_t g = base + (size_t)row * NPIX + ncol;
        uint4 k0 = *(const uint4*)&kb[g + c8];
        uint4 k1 = *(const uint4*)&kb[g + c8 + 32];
        *(uint4*)&ks[row * LKV + c8]      = k0;
        *(uint4*)&ks[row * LKV + c8 + 32] = k1;
        *(uint4*)&vs[row * LKV + c8]      = *(const uint4*)&vb[g + c8];
        *(uint4*)&vs[row * LKV + c8 + 32] = *(const uint4*)&vb[g + c8 + 32];
        const unsigned short* kp0 = (const unsigned short*)&k0;
        const unsigned short* kp1 = (const unsigned short*)&k1;
#pragma unroll
        for (int j = 0; j < 8; j++) ksacc += bf2f(kp0[j]) + bf2f(kp1[j]);
        __syncthreads();
#pragma unroll
        for (int ks32 = 0; ks32 < 2; ks32++) {
            bf16x8 bfv = *(const bf16x8*)&vs[(wave * 16 + lrow) * LKV + ks32 * 32 + quad * 8];
#pragma unroll
            for (int mt = 0; mt < 4; mt++) {
                bf16x8 af = *(const bf16x8*)&ks[(mt * 16 + lrow) * LKV + ks32 * 32 + quad * 8];
                acc[mt] = __builtin_amdgcn_mfma_f32_16x16x32_bf16(af, bfv, acc[mt], 0, 0, 0);
            }
        }
        __syncthreads();
    }

    // acc element = kv[d = mt*16+quad*4+r][e = wave*16+lrow]; store TRANSPOSED [e][d]
    float* kvb = kvT + (size_t)bh * 4096;
#pragma unroll
    for (int mt = 0; mt < 4; mt++)
#pragma unroll
        for (int r = 0; r < 4; r++)
            atomicAdd(&kvb[(wave * 16 + lrow) * 64 + mt * 16 + quad * 4 + r], acc[mt][r]);
    atomicAdd(&ksum[bh * 64 + row], ksacc);
}

// ---------------- K3: fused out+y ----------------
// grid (32 pixel-tiles, 2 o-halves, 8 b), block 256 (4 waves).
// Per h: GEMM1 out[128pix][64e]=z*(q kvT) -> LDS; GEMM2 y[o128][pix128] += Wo*out.
__global__ __launch_bounds__(256) void k_oy(
    const unsigned short* __restrict__ qT,    // B x 4096 x 512
    const float* __restrict__ kvT,            // 64bh x [e][d]
    const float* __restrict__ ksum,           // 64bh x 64
    const unsigned short* __restrict__ Wob,   // 256 x 512 bf16
    const float* __restrict__ bout,           // 256
    float* __restrict__ y)                    // B x 256 x 4096
{
    const int p0 = blockIdx.x * 128, oh = blockIdx.y, b = blockIdx.z;
    const int t = threadIdx.x, wave = t >> 6, lane = t & 63;
    const int l31 = lane & 31, lhi = lane >> 5;
    const int wm = wave >> 1, wn = wave & 1;

    __shared__ unsigned short Aq[128 * 72];   // q slice; reused as out-chunk
    __shared__ unsigned short Bv[96 * 72];    // kvT bf16 (e rows) + ksum hi/lo + zeros
    __shared__ unsigned short Wo[128 * 64];   // Wout slice rows oh*128.., XOR-swizzled

    for (int i = t; i < 30 * 64; i += 256)    // zero den-pad rows 66..95 (persist)
        Bv[(66 + (i >> 6)) * 72 + (i & 63)] = 0;

    f32x16 acc2[2][2];
#pragma unroll
    for (int i = 0; i < 2; i++)
#pragma unroll
        for (int j = 0; j < 2; j++)
#pragma unroll
            for (int r = 0; r < 16; r++) acc2[i][j][r] = 0.f;

    for (int h = 0; h < 8; h++) {
        const int bh = b * 8 + h;
        // --- stage q slice [128 pix][64 d]
        const unsigned short* qg = qT + ((size_t)b * NPIX + p0) * HIDC + h * 64;
#pragma unroll
        for (int i = 0; i < 4; i++) {
            int idx = t + i * 256;
            int row = idx >> 3, c8 = (idx & 7) * 8;
            *(uint4*)&Aq[row * 72 + c8] = *(const uint4*)&qg[(size_t)row * HIDC + c8];
        }
        // --- stage kvT -> bf16 [e][d]
        const float* kvg = kvT + (size_t)bh * 4096;
#pragma unroll
        for (int i = 0; i < 4; i++) {
            int idx = t + i * 256;
            int e = idx >> 4, d4 = (idx & 15) * 4;
            float4 v = *(const float4*)&kvg[e * 64 + d4];
            ushort4 o; o.x = f2bf(v.x); o.y = f2bf(v.y); o.z = f2bf(v.z); o.w = f2bf(v.w);
            *(ushort4*)&Bv[e * 72 + d4] = o;
        }
        if (t < 64) {
            float ksv = ksum[bh * 64 + t];
            unsigned short hi = f2bf(ksv);
            Bv[64 * 72 + t] = hi;
            Bv[65 * 72 + t] = f2bf(ksv - bf2f(hi));
        }
        // --- stage Wout slice [128 o][64 e], XOR swizzle on 16B chunks
#pragma unroll
        for (int i = 0; i < 4; i++) {
            int idx = t + i * 256;
            int o = idx >> 3, c = idx & 7;
            *(uint4*)&Wo[o * 64 + ((c ^ (o & 7)) * 8)] =
                *(const uint4*)&Wob[(size_t)(oh * 128 + o) * HIDC + h * 64 + c * 8];
        }
        __syncthreads();

        // --- GEMM1: D[m=pix32/wave][n=e64 + den], K=64
        f32x16 a1[3];
#pragma unroll
        for (int j = 0; j < 3; j++)
#pragma unroll
            for (int r = 0; r < 16; r++) a1[j][r] = 0.f;
#pragma unroll
        for (int ksb = 0; ksb < 4; ksb++) {
            int koff = ksb * 16 + lhi * 8;
            bf16x8 af = *(const bf16x8*)&Aq[(wave * 32 + l31) * 72 + koff];
#pragma unroll
            for (int nf = 0; nf < 3; nf++) {
                bf16x8 bg = *(const bf16x8*)&Bv[(nf * 32 + l31) * 72 + koff];
                a1[nf] = __builtin_amdgcn_mfma_f32_32x32x16_bf16(af, bg, a1[nf], 0, 0, 0);
            }
        }
        __syncthreads();   // all GEMM1 Aq reads complete before overwrite

        // --- z-scale, write out-chunk into Aq space [pix][e]
#pragma unroll
        for (int r = 0; r < 16; r++) {
            float hi = __shfl(a1[2][r], lane & 32);
            float lo = __shfl(a1[2][r], (lane & 32) | 1);
            float z = 1.f / (hi + lo + 1e-6f);
            int prow = (r & 3) + 8 * (r >> 2) + 4 * lhi;
#pragma unroll
            for (int nf = 0; nf < 2; nf++)
                Aq[(wave * 32 + prow) * 72 + nf * 32 + l31] = f2bf(a1[nf][r] * z);
        }
        __syncthreads();

        // --- GEMM2: D[m=o][n=pix] += Wo[o][e] * out[pix][e], K=64
#pragma unroll
        for (int ksb = 0; ksb < 4; ksb++) {
            int koff = ksb * 16 + lhi * 8;
            bf16x8 bg[2];
#pragma unroll
            for (int fn = 0; fn < 2; fn++)
                bg[fn] = *(const bf16x8*)&Aq[(wn * 64 + fn * 32 + l31) * 72 + koff];
            int wchunk = ((ksb * 2 + lhi) ^ (l31 & 7)) * 8;
#pragma unroll
            for (int fm = 0; fm < 2; fm++) {
                bf16x8 ag = *(const bf16x8*)&Wo[(wm * 64 + fm * 32 + l31) * 64 + wchunk];
#pragma unroll
                for (int fn = 0; fn < 2; fn++)
                    acc2[fm][fn] = __builtin_amdgcn_mfma_f32_32x32x16_bf16(
                        ag, bg[fn], acc2[fm][fn], 0, 0, 0);
            }
        }
        __syncthreads();   // before next-h staging overwrites LDS
    }

    // --- epilogue: y[o][pix] = acc2 + bias; 32-lane 128B fp32 runs
#pragma unroll
    for (int fm = 0; fm < 2; fm++) {
#pragma unroll
        for (int r = 0; r < 16; r++) {
            int orow = oh * 128 + wm * 64 + fm * 32 + (r & 3) + 8 * (r >> 2) + 4 * lhi;
            float bias = bout[orow];
#pragma unroll
            for (int fn = 0; fn < 2; fn++)
                y[((size_t)b * DIMC + orow) * NPIX + p0 + wn * 64 + fn * 32 + l31] =
                    acc2[fm][fn][r] + bias;
        }
    }
}

extern "C" void kernel_launch(void* const* d_in, const int* in_sizes, int n_in,
                              void* d_out, int out_size, void* d_ws, size_t ws_size,
                              hipStream_t stream) {
    (void)in_sizes; (void)n_in; (void)out_size; (void)ws_size;
    const float* x    = (const float*)d_in[0];
    const float* cm   = (const float*)d_in[1];
    const float* Wqkv = (const float*)d_in[2];
    const float* Wout = (const float*)d_in[3];
    const float* bout = (const float*)d_in[4];
    const float* csp  = (const float*)d_in[5];
    float* y = (float*)d_out;

    const size_t qn = (size_t)BATCH * HIDC * NPIX;
    char* ws = (char*)d_ws;
    unsigned short* qT  = (unsigned short*)ws;                  ws += qn * 2;
    unsigned short* kb  = (unsigned short*)ws;                  ws += qn * 2;
    unsigned short* vb  = (unsigned short*)ws;                  ws += qn * 2;
    unsigned short* xT  = (unsigned short*)ws;                  ws += qn * 2;
    float* kvp   = (float*)ws;                                  ws += (size_t)64 * 64 * 64 * 4;
    float* ksump = (float*)ws;                                  ws += (size_t)64 * 64 * 4;
    unsigned short* Wb  = (unsigned short*)ws;                  ws += (size_t)1536 * 256 * 2;
    unsigned short* Wob = (unsigned short*)ws;

    hipMemsetAsync(kvp, 0, ((size_t)64 * 64 * 64 + 64 * 64) * sizeof(float), stream);
    k_convW<<<512, 256, 0, stream>>>(Wqkv, Wout, Wb, Wob);
    k_tx  <<<dim3(128, 8, 8), 256, 0, stream>>>(x, xT);
    k_qkv <<<dim3(32, 12, 8), 256, 0, stream>>>(xT, Wb, cm, csp, qT, kb, vb);
    k_kv  <<<dim3(8, 64),     256, 0, stream>>>(kb, vb, kvp, ksump);
    k_oy  <<<dim3(32, 2, 8),  256, 0, stream>>>(qT, kvp, ksump, Wob, bout, y);
}